// Round 1
// baseline (29228.503 us; speedup 1.0000x reference)
//
#include <hip/hip_runtime.h>
#include <cmath>

typedef _Float16 f16;
typedef _Float16 f16x8 __attribute__((ext_vector_type(8)));
typedef float f32x4 __attribute__((ext_vector_type(4)));

#define NR 2048
#define NU 80
#define NUP 96          // NU padded to multiple of 32
#define NB 32           // batch
#define NS 1024         // seq len
#define NWG 128         // 64 col-groups x 2 batch-groups
#define ALPHA 0.6f
#define SIGMA_B 1.6f

// workspace layout (bytes)
#define OFF_AF   0ull                            // A as fp16 [2048][2048] : 8 MiB
#define OFF_XP   (OFF_AF  + (size_t)NR*NR*2)     // input fp16 [s][b][96]  : 6 MiB
#define OFF_BP   (OFF_XP  + (size_t)NS*NB*NUP*2) // B fp16 [2048][96]      : 384 KiB
#define OFF_RB0  (OFF_BP  + (size_t)NR*NUP*2)    // r bcast buf 0 fp16 [32][2048]
#define OFF_RB1  (OFF_RB0 + (size_t)NB*NR*2)     // r bcast buf 1
#define OFF_BAR  (OFF_RB1 + (size_t)NB*NR*2)     // barrier (cnt, gen)

__global__ void prep_kernel(const float* __restrict__ input,
                            const float* __restrict__ r0,
                            const float* __restrict__ A,
                            const float* __restrict__ B,
                            f16* __restrict__ Af, f16* __restrict__ xp,
                            f16* __restrict__ Bp, f16* __restrict__ rb0)
{
    const int stride = gridDim.x * blockDim.x;
    const int tid = blockIdx.x * blockDim.x + threadIdx.x;
    for (int i = tid; i < NR * NR; i += stride) Af[i] = (f16)A[i];
    for (int i = tid; i < NS * NB * NUP; i += stride) {
        int u = i % NUP; int sb = i / NUP; int b = sb % NB; int s = sb / NB;
        xp[i] = (u < NU) ? (f16)input[((size_t)b * NS + s) * NU + u] : (f16)0.0f;
    }
    for (int i = tid; i < NR * NUP; i += stride) {
        int u = i % NUP; int j = i / NUP;
        Bp[i] = (u < NU) ? (f16)B[j * NU + u] : (f16)0.0f;
    }
    for (int i = tid; i < NB * NR; i += stride) rb0[i] = (f16)r0[i];
}

// Persistent scan kernel. 128 WGs x 256 threads (4 waves).
// WG wg: batch-group bg = wg&1 (rows bg*16..+16), col-group cg = wg>>1 (cols cg*32..+32).
// Waves: ntile = wid&1 (16-col half), kh = wid>>1 (K half: kh*1024..+1024).
// Each wave holds its A-slice as 32 MFMA B-operand fragments in registers (128 VGPRs),
// immune to the per-step L1/L2 invalidation the cross-XCD fences require.
__global__ __launch_bounds__(256, 1) void scan_kernel(
    float* __restrict__ out,
    const float* __restrict__ r0,
    const f16* __restrict__ Af, const f16* __restrict__ xp,
    const f16* __restrict__ Bp, f16* __restrict__ rb0a, f16* __restrict__ rb1a,
    int* __restrict__ bar)
{
    const int tid   = threadIdx.x;
    const int lane  = tid & 63;
    const int wid   = tid >> 6;
    const int ntile = wid & 1;
    const int kh    = wid >> 1;
    const int wg    = blockIdx.x;
    const int cg    = wg >> 1;
    const int bg    = wg & 1;
    const int row0  = bg * 16;
    const int col0  = cg * 32 + ntile * 16;

    const int fr = lane & 15;   // fragment row/col index
    const int kg = lane >> 4;   // k-group (8 halves each)

    __shared__ f32x4 lds_part[2 * 64];

    // ---- A-matrix slice -> registers, already in B^T fragment layout:
    // bfrag[kk] lane l elem j = A[col0 + (l&15)][kh*1024 + kk*32 + (l>>4)*8 + j]
    f16x8 bfrag[32];
    {
        const f16* base = Af + (size_t)(col0 + fr) * NR + kh * 1024 + kg * 8;
        #pragma unroll
        for (int kk = 0; kk < 32; ++kk)
            bfrag[kk] = *(const f16x8*)(base + kk * 32);
    }
    // ---- input-projection B slice (kh==1 waves use it; K = 96 padded)
    f16x8 bpfrag[3];
    {
        const f16* base = Bp + (size_t)(col0 + fr) * NUP + kg * 8;
        #pragma unroll
        for (int kk = 0; kk < 3; ++kk)
            bpfrag[kk] = *(const f16x8*)(base + kk * 32);
    }

    // ---- fp32 master state for owned outputs (kh==0 waves own the tile)
    // D layout: col = lane&15, row = (lane>>4)*4 + i   [measured m89]
    float rmaster[4];
    #pragma unroll
    for (int i = 0; i < 4; ++i) {
        int brow = row0 + kg * 4 + i;
        rmaster[i] = r0[(size_t)brow * NR + (col0 + fr)];
    }

    f16* rcur = rb0a;
    f16* rnxt = rb1a;

    for (int s = 0; s < NS; ++s) {
        f32x4 acc = {0.f, 0.f, 0.f, 0.f};
        // a_frag: lane l reads r[row0 + (l&15)][kh*1024 + kk*32 + (l>>4)*8 ..+7]
        const f16* rbase = rcur + (size_t)(row0 + fr) * NR + kh * 1024 + kg * 8;
        #pragma unroll
        for (int kk = 0; kk < 32; ++kk) {
            f16x8 a = *(const f16x8*)(rbase + kk * 32);
            acc = __builtin_amdgcn_mfma_f32_16x16x32_f16(a, bfrag[kk], acc, 0, 0, 0);
        }
        if (kh) {
            // fold input projection: S += x[s] @ B^T (K = 96)
            const f16* xbase = xp + ((size_t)s * NB + (row0 + fr)) * NUP + kg * 8;
            #pragma unroll
            for (int kk = 0; kk < 3; ++kk) {
                f16x8 a = *(const f16x8*)(xbase + kk * 32);
                acc = __builtin_amdgcn_mfma_f32_16x16x32_f16(a, bpfrag[kk], acc, 0, 0, 0);
            }
            lds_part[ntile * 64 + lane] = acc;
        }
        __syncthreads();
        if (!kh) {
            f32x4 other = lds_part[ntile * 64 + lane];
            float rnew[4];
            #pragma unroll
            for (int i = 0; i < 4; ++i) {
                float sval = acc[i] + other[i] + SIGMA_B;
                float rn = (1.0f - ALPHA) * rmaster[i] + ALPHA * tanhf(sval);
                rmaster[i] = rn;
                rnew[i] = rn;
            }
            #pragma unroll
            for (int i = 0; i < 4; ++i) {
                int brow = row0 + kg * 4 + i;
                int gcol = col0 + fr;
                __builtin_nontemporal_store(rnew[i],
                    out + ((size_t)brow * NS + s) * NR + gcol);
                rnxt[(size_t)brow * NR + gcol] = (f16)rnew[i];
            }
        }
        if (s != NS - 1) {
            // ---- grid barrier (release: wb L2; acquire: inv L1/L2) ----
            __threadfence();
            __syncthreads();
            if (tid == 0) {
                int g = __hip_atomic_load(bar + 1, __ATOMIC_RELAXED, __HIP_MEMORY_SCOPE_AGENT);
                int old = __hip_atomic_fetch_add(bar, 1, __ATOMIC_ACQ_REL, __HIP_MEMORY_SCOPE_AGENT);
                if (old == NWG - 1) {
                    __hip_atomic_store(bar, 0, __ATOMIC_RELAXED, __HIP_MEMORY_SCOPE_AGENT);
                    __hip_atomic_fetch_add(bar + 1, 1, __ATOMIC_RELEASE, __HIP_MEMORY_SCOPE_AGENT);
                } else {
                    while (__hip_atomic_load(bar + 1, __ATOMIC_RELAXED, __HIP_MEMORY_SCOPE_AGENT) == g)
                        __builtin_amdgcn_s_sleep(2);
                }
            }
            __syncthreads();
            __threadfence();
        }
        f16* t = rcur; rcur = rnxt; rnxt = t;
    }

    // ---- final state r_final (1, 32, 2048) appended after reservoir
    if (!kh) {
        #pragma unroll
        for (int i = 0; i < 4; ++i) {
            int brow = row0 + kg * 4 + i;
            out[(size_t)NB * NS * NR + (size_t)brow * NR + (col0 + fr)] = rmaster[i];
        }
    }
}

extern "C" void kernel_launch(void* const* d_in, const int* in_sizes, int n_in,
                              void* d_out, int out_size, void* d_ws, size_t ws_size,
                              hipStream_t stream)
{
    const float* input = (const float*)d_in[0];
    const float* r0    = (const float*)d_in[1];
    const float* A     = (const float*)d_in[2];
    const float* B     = (const float*)d_in[3];
    float* out = (float*)d_out;
    char* ws = (char*)d_ws;

    f16* Af  = (f16*)(ws + OFF_AF);
    f16* xp  = (f16*)(ws + OFF_XP);
    f16* Bp  = (f16*)(ws + OFF_BP);
    f16* rb0 = (f16*)(ws + OFF_RB0);
    f16* rb1 = (f16*)(ws + OFF_RB1);
    int* bar = (int*)(ws + OFF_BAR);

    hipMemsetAsync(bar, 0, 256, stream);
    prep_kernel<<<2048, 256, 0, stream>>>(input, r0, A, B, Af, xp, Bp, rb0);
    scan_kernel<<<NWG, 256, 0, stream>>>(out, r0, Af, xp, Bp, rb0, rb1, bar);
}

// Round 2
// 12937.656 us; speedup vs baseline: 2.2592x; 2.2592x over previous
//
#include <hip/hip_runtime.h>
#include <cmath>

typedef _Float16 f16;
typedef _Float16 f16x8 __attribute__((ext_vector_type(8)));
typedef float f32x4 __attribute__((ext_vector_type(4)));

#define NR 2048
#define NU 80
#define NUP 96          // NU padded to multiple of 32
#define NB 32           // batch
#define NS 1024         // seq len
#define NWG 128         // 64 col-groups x 2 batch-groups
#define ALPHA 0.6f
#define SIGMA_B 1.6f

// flags: one per WG, padded to 64B to avoid store serialization on shared lines
#define FLAG_STRIDE 16   // ints
#define FLAGS_BYTES (NWG * FLAG_STRIDE * 4)

// workspace layout (bytes)
#define OFF_AF   0ull                            // A as fp16 [2048][2048] : 8 MiB
#define OFF_XP   (OFF_AF  + (size_t)NR*NR*2)     // input fp16 [s][b][96]  : 6 MiB
#define OFF_BP   (OFF_XP  + (size_t)NS*NB*NUP*2) // B fp16 [2048][96]      : 384 KiB
#define OFF_RB0  (OFF_BP  + (size_t)NR*NUP*2)    // r bcast buf 0 fp16 [32][2048]
#define OFF_RB1  (OFF_RB0 + (size_t)NB*NR*2)     // r bcast buf 1
#define OFF_FLG  (OFF_RB1 + (size_t)NB*NR*2)     // flag array

__global__ void prep_kernel(const float* __restrict__ input,
                            const float* __restrict__ r0,
                            const float* __restrict__ A,
                            const float* __restrict__ B,
                            f16* __restrict__ Af, f16* __restrict__ xp,
                            f16* __restrict__ Bp, f16* __restrict__ rb0)
{
    const int stride = gridDim.x * blockDim.x;
    const int tid = blockIdx.x * blockDim.x + threadIdx.x;
    for (int i = tid; i < NR * NR; i += stride) Af[i] = (f16)A[i];
    for (int i = tid; i < NS * NB * NUP; i += stride) {
        int u = i % NUP; int sb = i / NUP; int b = sb % NB; int s = sb / NB;
        xp[i] = (u < NU) ? (f16)input[((size_t)b * NS + s) * NU + u] : (f16)0.0f;
    }
    for (int i = tid; i < NR * NUP; i += stride) {
        int u = i % NUP; int j = i / NUP;
        Bp[i] = (u < NU) ? (f16)B[j * NU + u] : (f16)0.0f;
    }
    for (int i = tid; i < NB * NR; i += stride) rb0[i] = (f16)r0[i];
}

// Persistent scan kernel. 128 WGs x 256 threads (4 waves).
// WG wg: batch-group bg = wg&1 (rows bg*16..+16), col-group cg = wg>>1 (cols cg*32..+32).
// The two bg chains are fully independent: bg=0 WGs only produce/consume rows 0..15.
// Waves: ntile = wid&1 (16-col half), kh = wid>>1 (K half: kh*1024..+1024).
// Each wave holds its A-slice as 32 MFMA B-operand fragments in registers.
__global__ __launch_bounds__(256, 1) void scan_kernel(
    float* __restrict__ out,
    const float* __restrict__ r0,
    const f16* __restrict__ Af, const f16* __restrict__ xp,
    const f16* __restrict__ Bp, f16* __restrict__ rb0a, f16* __restrict__ rb1a,
    int* __restrict__ flags)
{
    const int tid   = threadIdx.x;
    const int lane  = tid & 63;
    const int wid   = tid >> 6;
    const int ntile = wid & 1;
    const int kh    = wid >> 1;
    const int wg    = blockIdx.x;
    const int cg    = wg >> 1;
    const int bg    = wg & 1;
    const int row0  = bg * 16;
    const int col0  = cg * 32 + ntile * 16;

    const int fr = lane & 15;   // fragment row/col index
    const int kg = lane >> 4;   // k-group (8 halves each)

    __shared__ f32x4 lds_part[2 * 64];

    // ---- A-matrix slice -> registers, already in B^T fragment layout:
    // bfrag[kk] lane l elem j = A[col0 + (l&15)][kh*1024 + kk*32 + (l>>4)*8 + j]
    f16x8 bfrag[32];
    {
        const f16* base = Af + (size_t)(col0 + fr) * NR + kh * 1024 + kg * 8;
        #pragma unroll
        for (int kk = 0; kk < 32; ++kk)
            bfrag[kk] = *(const f16x8*)(base + kk * 32);
    }
    // Pin fragments in registers: forbid rematerialization of the global loads
    // (post-fence reloads would come from L3 every step).
    #pragma unroll
    for (int kk = 0; kk < 32; ++kk)
        asm volatile("" : "+v"(bfrag[kk]));

    // ---- input-projection B slice (kh==1 waves use it; K = 96 padded)
    f16x8 bpfrag[3];
    {
        const f16* base = Bp + (size_t)(col0 + fr) * NUP + kg * 8;
        #pragma unroll
        for (int kk = 0; kk < 3; ++kk)
            bpfrag[kk] = *(const f16x8*)(base + kk * 32);
        #pragma unroll
        for (int kk = 0; kk < 3; ++kk)
            asm volatile("" : "+v"(bpfrag[kk]));
    }

    // ---- fp32 master state for owned outputs (kh==0 waves own the tile)
    // D layout: col = lane&15, row = (lane>>4)*4 + i
    float rmaster[4];
    #pragma unroll
    for (int i = 0; i < 4; ++i) {
        int brow = row0 + kg * 4 + i;
        rmaster[i] = r0[(size_t)brow * NR + (col0 + fr)];
    }

    f16* rcur = rb0a;
    f16* rnxt = rb1a;

    // my flag slot and my dependency group's flag base (64 WGs sharing my bg)
    int* myflag = flags + (size_t)(bg * 64 + cg) * FLAG_STRIDE;
    int* grpflags = flags + (size_t)(bg * 64) * FLAG_STRIDE;

    for (int s = 0; s < NS; ++s) {
        // 4 independent accumulators to break the MFMA dependency chain (32 -> 8 deep)
        f32x4 a0 = {0,0,0,0}, a1 = {0,0,0,0}, a2 = {0,0,0,0}, a3 = {0,0,0,0};
        const f16* rbase = rcur + (size_t)(row0 + fr) * NR + kh * 1024 + kg * 8;
        #pragma unroll
        for (int kk = 0; kk < 32; kk += 4) {
            f16x8 x0 = *(const f16x8*)(rbase + (kk + 0) * 32);
            f16x8 x1 = *(const f16x8*)(rbase + (kk + 1) * 32);
            f16x8 x2 = *(const f16x8*)(rbase + (kk + 2) * 32);
            f16x8 x3 = *(const f16x8*)(rbase + (kk + 3) * 32);
            a0 = __builtin_amdgcn_mfma_f32_16x16x32_f16(x0, bfrag[kk + 0], a0, 0, 0, 0);
            a1 = __builtin_amdgcn_mfma_f32_16x16x32_f16(x1, bfrag[kk + 1], a1, 0, 0, 0);
            a2 = __builtin_amdgcn_mfma_f32_16x16x32_f16(x2, bfrag[kk + 2], a2, 0, 0, 0);
            a3 = __builtin_amdgcn_mfma_f32_16x16x32_f16(x3, bfrag[kk + 3], a3, 0, 0, 0);
        }
        if (kh) {
            // fold input projection: S += x[s] @ B^T (K = 96)
            const f16* xbase = xp + ((size_t)s * NB + (row0 + fr)) * NUP + kg * 8;
            #pragma unroll
            for (int kk = 0; kk < 3; ++kk) {
                f16x8 a = *(const f16x8*)(xbase + kk * 32);
                if (kk == 0) a0 = __builtin_amdgcn_mfma_f32_16x16x32_f16(a, bpfrag[kk], a0, 0, 0, 0);
                if (kk == 1) a1 = __builtin_amdgcn_mfma_f32_16x16x32_f16(a, bpfrag[kk], a1, 0, 0, 0);
                if (kk == 2) a2 = __builtin_amdgcn_mfma_f32_16x16x32_f16(a, bpfrag[kk], a2, 0, 0, 0);
            }
        }
        f32x4 acc = (a0 + a1) + (a2 + a3);
        if (kh) lds_part[ntile * 64 + lane] = acc;
        __syncthreads();                                   // (A) LDS visibility
        if (!kh) {
            f32x4 other = lds_part[ntile * 64 + lane];
            float rnew[4];
            #pragma unroll
            for (int i = 0; i < 4; ++i) {
                float sval = acc[i] + other[i] + SIGMA_B;
                float rn = (1.0f - ALPHA) * rmaster[i] + ALPHA * tanhf(sval);
                rmaster[i] = rn;
                rnew[i] = rn;
            }
            #pragma unroll
            for (int i = 0; i < 4; ++i) {
                int brow = row0 + kg * 4 + i;
                int gcol = col0 + fr;
                __builtin_nontemporal_store(rnew[i],
                    out + ((size_t)brow * NS + s) * NR + gcol);
                rnxt[(size_t)brow * NR + gcol] = (f16)rnew[i];
            }
        }
        if (s != NS - 1) {
            __syncthreads();   // (B) all waves' stores drained to L2 (vmcnt0 at barrier)
            if (tid == 0) {
                __threadfence();   // wbl2: make rnxt visible agent-wide
                __hip_atomic_store(myflag, s + 1, __ATOMIC_RELEASE,
                                   __HIP_MEMORY_SCOPE_AGENT);
            }
            if (wid == 0) {
                // lane l polls WG (bg, l)'s flag; all 64 loads in flight per iter
                int* f = grpflags + lane * FLAG_STRIDE;
                while (__hip_atomic_load(f, __ATOMIC_RELAXED,
                                         __HIP_MEMORY_SCOPE_AGENT) < s + 1)
                    __builtin_amdgcn_s_sleep(1);
                __threadfence();   // acquire: invalidate L1/L2 before next r loads
            }
            __syncthreads();   // (C) release all waves into next step
        }
        f16* t = rcur; rcur = rnxt; rnxt = t;
    }

    // ---- final state r_final (1, 32, 2048) appended after reservoir
    if (!kh) {
        #pragma unroll
        for (int i = 0; i < 4; ++i) {
            int brow = row0 + kg * 4 + i;
            out[(size_t)NB * NS * NR + (size_t)brow * NR + (col0 + fr)] = rmaster[i];
        }
    }
}

extern "C" void kernel_launch(void* const* d_in, const int* in_sizes, int n_in,
                              void* d_out, int out_size, void* d_ws, size_t ws_size,
                              hipStream_t stream)
{
    const float* input = (const float*)d_in[0];
    const float* r0    = (const float*)d_in[1];
    const float* A     = (const float*)d_in[2];
    const float* B     = (const float*)d_in[3];
    float* out = (float*)d_out;
    char* ws = (char*)d_ws;

    f16* Af  = (f16*)(ws + OFF_AF);
    f16* xp  = (f16*)(ws + OFF_XP);
    f16* Bp  = (f16*)(ws + OFF_BP);
    f16* rb0 = (f16*)(ws + OFF_RB0);
    f16* rb1 = (f16*)(ws + OFF_RB1);
    int* flg = (int*)(ws + OFF_FLG);

    hipMemsetAsync(flg, 0, FLAGS_BYTES, stream);
    prep_kernel<<<2048, 256, 0, stream>>>(input, r0, A, B, Af, xp, Bp, rb0);
    scan_kernel<<<NWG, 256, 0, stream>>>(out, r0, Af, xp, Bp, rb0, rb1, flg);
}

// Round 3
// 6181.838 us; speedup vs baseline: 4.7281x; 2.0928x over previous
//
#include <hip/hip_runtime.h>
#include <cmath>

typedef _Float16 f16;
typedef _Float16 f16x8 __attribute__((ext_vector_type(8)));
typedef float f32x4 __attribute__((ext_vector_type(4)));

#define NR 2048
#define NU 80
#define NUP 96          // NU padded to multiple of 32
#define NB 32           // batch
#define NS 1024         // seq len
#define NWG 128         // 64 col-groups x 2 batch-groups
#define ALPHA 0.6f
#define SIGMA_B 1.6f

// flags: one per WG, padded to 64B
#define FLAG_STRIDE 16   // ints
#define FLAGS_BYTES (NWG * FLAG_STRIDE * 4)

// workspace layout (bytes)
#define OFF_AF   0ull                            // A as fp16 [2048][2048] : 8 MiB
#define OFF_XP   (OFF_AF  + (size_t)NR*NR*2)     // input fp16 [s][b][96]  : 6 MiB
#define OFF_BP   (OFF_XP  + (size_t)NS*NB*NUP*2) // B fp16 [2048][96]      : 384 KiB
#define OFF_RB0  (OFF_BP  + (size_t)NR*NUP*2)    // r bcast buf 0 fp16 [32][2048]
#define OFF_RB1  (OFF_RB0 + (size_t)NB*NR*2)     // r bcast buf 1
#define OFF_FLG  (OFF_RB1 + (size_t)NB*NR*2)     // flag array

__global__ void prep_kernel(const float* __restrict__ input,
                            const float* __restrict__ r0,
                            const float* __restrict__ A,
                            const float* __restrict__ B,
                            f16* __restrict__ Af, f16* __restrict__ xp,
                            f16* __restrict__ Bp, f16* __restrict__ rb0)
{
    const int stride = gridDim.x * blockDim.x;
    const int tid = blockIdx.x * blockDim.x + threadIdx.x;
    for (int i = tid; i < NR * NR; i += stride) Af[i] = (f16)A[i];
    for (int i = tid; i < NS * NB * NUP; i += stride) {
        int u = i % NUP; int sb = i / NUP; int b = sb % NB; int s = sb / NB;
        xp[i] = (u < NU) ? (f16)input[((size_t)b * NS + s) * NU + u] : (f16)0.0f;
    }
    for (int i = tid; i < NR * NUP; i += stride) {
        int u = i % NUP; int j = i / NUP;
        Bp[i] = (u < NU) ? (f16)B[j * NU + u] : (f16)0.0f;
    }
    for (int i = tid; i < NB * NR; i += stride) rb0[i] = (f16)r0[i];
}

// device-coherent 16B load: bypass L1/L2, read from coherence point.
template <int BYTEOFF>
__device__ inline f16x8 load_sc(const f16* base) {
    f16x8 v;
    asm volatile("global_load_dwordx4 %0, %1, off offset:%2 sc0 sc1"
                 : "=v"(v) : "v"(base), "n"(BYTEOFF) : "memory");
    return v;
}
// device-coherent 4B store: write through to coherence point.
__device__ inline void store_sc(int* p, int v) {
    asm volatile("global_store_dword %0, %1, off sc0 sc1"
                 :: "v"(p), "v"(v) : "memory");
}

// Persistent scan kernel. 128 WGs x 256 threads (4 waves).
// WG wg: bg = wg&1 (batch rows bg*16..+16), cg = wg>>1 (cols cg*32..+32).
// The two bg chains are fully independent (separate flag groups).
// Waves: ntile = wid&1 (16-col half), kh = wid>>1 (K half).
// A-slice lives in registers (32 B-operand fragments / wave); cross-WG r state
// moves via sc0sc1 accesses only -- NO cache-wide fences anywhere.
__global__ __launch_bounds__(256, 1) void scan_kernel(
    float* __restrict__ out,
    const float* __restrict__ r0,
    const f16* __restrict__ Af, const f16* __restrict__ xp,
    const f16* __restrict__ Bp, f16* __restrict__ rb0a, f16* __restrict__ rb1a,
    int* __restrict__ flags)
{
    const int tid   = threadIdx.x;
    const int lane  = tid & 63;
    const int wid   = tid >> 6;
    const int ntile = wid & 1;
    const int kh    = wid >> 1;
    const int wg    = blockIdx.x;
    const int cg    = wg >> 1;
    const int bg    = wg & 1;
    const int row0  = bg * 16;
    const int col0  = cg * 32 + ntile * 16;

    const int fr = lane & 15;   // fragment row/col index
    const int kg = lane >> 4;   // k-group (8 halves each)

    __shared__ f32x4 lds_part[2 * 64];
    __shared__ f16   lds_r[16][32];   // rnew repack tile for coalesced sc stores

    // ---- A-matrix slice -> registers (B^T fragment layout)
    f16x8 bfrag[32];
    {
        const f16* base = Af + (size_t)(col0 + fr) * NR + kh * 1024 + kg * 8;
        #pragma unroll
        for (int kk = 0; kk < 32; ++kk)
            bfrag[kk] = *(const f16x8*)(base + kk * 32);
    }
    #pragma unroll
    for (int kk = 0; kk < 32; ++kk)
        asm volatile("" : "+v"(bfrag[kk]));    // pin: no remat

    // ---- input-projection B slice (kh==1 waves; K = 96 padded)
    f16x8 bpfrag[3];
    {
        const f16* base = Bp + (size_t)(col0 + fr) * NUP + kg * 8;
        #pragma unroll
        for (int kk = 0; kk < 3; ++kk)
            bpfrag[kk] = *(const f16x8*)(base + kk * 32);
        #pragma unroll
        for (int kk = 0; kk < 3; ++kk)
            asm volatile("" : "+v"(bpfrag[kk]));
    }

    // ---- fp32 master state (kh==0 waves own the output tile)
    float rmaster[4];
    #pragma unroll
    for (int i = 0; i < 4; ++i) {
        int brow = row0 + kg * 4 + i;
        rmaster[i] = r0[(size_t)brow * NR + (col0 + fr)];
    }

    f16* rcur = rb0a;
    f16* rnxt = rb1a;

    int* myflag   = flags + (size_t)(bg * 64 + cg) * FLAG_STRIDE;
    int* grpflags = flags + (size_t)(bg * 64) * FLAG_STRIDE;

    for (int s = 0; s < NS; ++s) {
        f32x4 a0 = {0,0,0,0}, a1 = {0,0,0,0}, a2 = {0,0,0,0}, a3 = {0,0,0,0};
        const f16* rbase = rcur + (size_t)(row0 + fr) * NR + kh * 1024 + kg * 8;

        // issue all 32 device-coherent loads (stay in flight), then counted
        // waits interleaved with MFMA groups.  vmcnt retires in order, so
        // vmcnt(31-j) guarantees my loads 0..j regardless of compiler vmem.
        f16x8 x[32];
        #define LD(i) x[i] = load_sc<(i) * 64>(rbase)
        LD(0); LD(1); LD(2); LD(3); LD(4); LD(5); LD(6); LD(7);
        LD(8); LD(9); LD(10); LD(11); LD(12); LD(13); LD(14); LD(15);
        LD(16); LD(17); LD(18); LD(19); LD(20); LD(21); LD(22); LD(23);
        LD(24); LD(25); LD(26); LD(27); LD(28); LD(29); LD(30); LD(31);
        #undef LD
        #define MF(i, A) A = __builtin_amdgcn_mfma_f32_16x16x32_f16(x[i], bfrag[i], A, 0, 0, 0)
        asm volatile("s_waitcnt vmcnt(24)" ::: "memory");
        __builtin_amdgcn_sched_barrier(0);
        MF(0,a0); MF(1,a1); MF(2,a2); MF(3,a3); MF(4,a0); MF(5,a1); MF(6,a2); MF(7,a3);
        asm volatile("s_waitcnt vmcnt(16)" ::: "memory");
        __builtin_amdgcn_sched_barrier(0);
        MF(8,a0); MF(9,a1); MF(10,a2); MF(11,a3); MF(12,a0); MF(13,a1); MF(14,a2); MF(15,a3);
        asm volatile("s_waitcnt vmcnt(8)" ::: "memory");
        __builtin_amdgcn_sched_barrier(0);
        MF(16,a0); MF(17,a1); MF(18,a2); MF(19,a3); MF(20,a0); MF(21,a1); MF(22,a2); MF(23,a3);
        asm volatile("s_waitcnt vmcnt(0)" ::: "memory");
        __builtin_amdgcn_sched_barrier(0);
        MF(24,a0); MF(25,a1); MF(26,a2); MF(27,a3); MF(28,a0); MF(29,a1); MF(30,a2); MF(31,a3);
        #undef MF

        if (kh) {
            // fold input projection: S += x[s] @ B^T (K = 96); cached loads
            const f16* xbase = xp + ((size_t)s * NB + (row0 + fr)) * NUP + kg * 8;
            f16x8 p0 = *(const f16x8*)(xbase);
            f16x8 p1 = *(const f16x8*)(xbase + 32);
            f16x8 p2 = *(const f16x8*)(xbase + 64);
            a0 = __builtin_amdgcn_mfma_f32_16x16x32_f16(p0, bpfrag[0], a0, 0, 0, 0);
            a1 = __builtin_amdgcn_mfma_f32_16x16x32_f16(p1, bpfrag[1], a1, 0, 0, 0);
            a2 = __builtin_amdgcn_mfma_f32_16x16x32_f16(p2, bpfrag[2], a2, 0, 0, 0);
        }
        f32x4 acc = (a0 + a1) + (a2 + a3);
        if (kh) lds_part[ntile * 64 + lane] = acc;
        __syncthreads();                                   // (A)

        float rnew[4];
        if (!kh) {
            f32x4 other = lds_part[ntile * 64 + lane];
            #pragma unroll
            for (int i = 0; i < 4; ++i) {
                float sval = acc[i] + other[i] + SIGMA_B;
                float rn = (1.0f - ALPHA) * rmaster[i] + ALPHA * tanhf(sval);
                rmaster[i] = rn;
                rnew[i] = rn;
                lds_r[kg * 4 + i][ntile * 16 + fr] = (f16)rn;
            }
        }
        __syncthreads();                                   // (B) lds_r ready

        if (s != NS - 1) {
            // coalesced device-coherent publish of the 16x32 tile (1 KB)
            {
                int row = tid >> 4, dw = tid & 15;
                int val = *(const int*)&lds_r[row][dw * 2];
                store_sc((int*)(rnxt + (size_t)(row0 + row) * NR + cg * 32 + dw * 2), val);
            }
            asm volatile("s_waitcnt vmcnt(0)" ::: "memory");  // stores acked at CP
            __syncthreads();                               // (C) whole WG acked
            if (tid == 0)
                __hip_atomic_store(myflag, s + 1, __ATOMIC_RELAXED,
                                   __HIP_MEMORY_SCOPE_AGENT);
        }

        // output stream (plain cached/nt stores; off the flag critical path)
        if (!kh) {
            #pragma unroll
            for (int i = 0; i < 4; ++i) {
                int brow = row0 + kg * 4 + i;
                __builtin_nontemporal_store(rnew[i],
                    out + ((size_t)brow * NS + s) * NR + (col0 + fr));
            }
        }

        if (s != NS - 1) {
            if (wid == 0) {
                int* f = grpflags + lane * FLAG_STRIDE;
                int target = s + 1;
                while (true) {
                    int v = __hip_atomic_load(f, __ATOMIC_RELAXED,
                                              __HIP_MEMORY_SCOPE_AGENT);
                    if (__all(v >= target)) break;
                    __builtin_amdgcn_s_sleep(1);
                }
            }
            __syncthreads();                               // (D) release WG
        }
        f16* t = rcur; rcur = rnxt; rnxt = t;
    }

    // ---- final state r_final (1, 32, 2048)
    if (!kh) {
        #pragma unroll
        for (int i = 0; i < 4; ++i) {
            int brow = row0 + kg * 4 + i;
            out[(size_t)NB * NS * NR + (size_t)brow * NR + (col0 + fr)] = rmaster[i];
        }
    }
}

extern "C" void kernel_launch(void* const* d_in, const int* in_sizes, int n_in,
                              void* d_out, int out_size, void* d_ws, size_t ws_size,
                              hipStream_t stream)
{
    const float* input = (const float*)d_in[0];
    const float* r0    = (const float*)d_in[1];
    const float* A     = (const float*)d_in[2];
    const float* B     = (const float*)d_in[3];
    float* out = (float*)d_out;
    char* ws = (char*)d_ws;

    f16* Af  = (f16*)(ws + OFF_AF);
    f16* xp  = (f16*)(ws + OFF_XP);
    f16* Bp  = (f16*)(ws + OFF_BP);
    f16* rb0 = (f16*)(ws + OFF_RB0);
    f16* rb1 = (f16*)(ws + OFF_RB1);
    int* flg = (int*)(ws + OFF_FLG);

    hipMemsetAsync(flg, 0, FLAGS_BYTES, stream);
    prep_kernel<<<2048, 256, 0, stream>>>(input, r0, A, B, Af, xp, Bp, rb0);
    scan_kernel<<<NWG, 256, 0, stream>>>(out, r0, Af, xp, Bp, rb0, rb1, flg);
}

// Round 4
// 6021.576 us; speedup vs baseline: 4.8540x; 1.0266x over previous
//
#include <hip/hip_runtime.h>
#include <cmath>

typedef _Float16 f16;
typedef _Float16 f16x8 __attribute__((ext_vector_type(8)));
typedef float f32x4 __attribute__((ext_vector_type(4)));

#define NR 2048
#define NU 80
#define NUP 96          // NU padded to multiple of 32
#define NB 32           // batch
#define NS 1024         // seq len
#define NWG 64          // one WG per 32-col group; all 32 batch rows
#define ALPHA 0.6f
#define SIGMA_B 1.6f

#define FLAG_STRIDE 16   // ints (64B per flag)
#define FLAGS_BYTES (NWG * FLAG_STRIDE * 4)

// workspace layout (bytes)
#define OFF_AF   0ull                            // A as fp16 [2048][2048] : 8 MiB
#define OFF_XP   (OFF_AF  + (size_t)NR*NR*2)     // input fp16 [s][b][96]  : 6 MiB
#define OFF_BP   (OFF_XP  + (size_t)NS*NB*NUP*2) // B fp16 [2048][96]
#define OFF_RB0  (OFF_BP  + (size_t)NR*NUP*2)    // r bcast buf 0 fp16 [32][2048]
#define OFF_RB1  (OFF_RB0 + (size_t)NB*NR*2)     // r bcast buf 1
#define OFF_FLG  (OFF_RB1 + (size_t)NB*NR*2)     // flag array

__global__ void prep_kernel(const float* __restrict__ input,
                            const float* __restrict__ r0,
                            const float* __restrict__ A,
                            const float* __restrict__ B,
                            f16* __restrict__ Af, f16* __restrict__ xp,
                            f16* __restrict__ Bp, f16* __restrict__ rb0)
{
    const int stride = gridDim.x * blockDim.x;
    const int tid = blockIdx.x * blockDim.x + threadIdx.x;
    for (int i = tid; i < NR * NR; i += stride) Af[i] = (f16)A[i];
    for (int i = tid; i < NS * NB * NUP; i += stride) {
        int u = i % NUP; int sb = i / NUP; int b = sb % NB; int s = sb / NB;
        xp[i] = (u < NU) ? (f16)input[((size_t)b * NS + s) * NU + u] : (f16)0.0f;
    }
    for (int i = tid; i < NR * NUP; i += stride) {
        int u = i % NUP; int j = i / NUP;
        Bp[i] = (u < NU) ? (f16)B[j * NU + u] : (f16)0.0f;
    }
    for (int i = tid; i < NB * NR; i += stride) rb0[i] = (f16)r0[i];
}

#define MFMA(va, vb, vc) __builtin_amdgcn_mfma_f32_16x16x32_f16(va, vb, vc, 0, 0, 0)

// Persistent scan. 64 WGs x 256 threads. WG cg owns output cols cg*32..+32 for
// all 32 batch rows. Wave w = K-quarter kq (cols kq*512..+512 of r).
// Per-wave flag wait: wave kq needs only WGs [16kq,16kq+16) -> polls 16 flags,
// no grid-wide barrier. Double-buffer safety: each WG's 4 waves jointly cover
// all 64 flags before its publish (joined by the reduce __syncthreads), so no
// WG can lap another.
__global__ __launch_bounds__(256, 1) void scan_kernel(
    float* __restrict__ out,
    const float* __restrict__ r0,
    const f16* __restrict__ Af, const f16* __restrict__ xp,
    const f16* __restrict__ Bp, f16* __restrict__ rb0a, f16* __restrict__ rb1a,
    int* __restrict__ flags)
{
    const int tid  = threadIdx.x;
    const int lane = tid & 63;
    const int kq   = tid >> 6;        // K-quarter owned by this wave
    const int cg   = blockIdx.x;
    const int rt   = kq >> 1;         // owned output tile for epilogue
    const int ct   = kq & 1;

    const int fr = lane & 15;
    const int kg = lane >> 4;

    __shared__ f32x4 lds_part[4][4][64];   // [wave][tile][lane]
    __shared__ f16   lds_r[32 * 36];       // padded stride 36 halves (72B)

    // ---- A-slice -> registers (B^T fragment layout), 2 col-tiles x 16 k-frags
    f16x8 bf[2][16];
    #pragma unroll
    for (int c = 0; c < 2; ++c) {
        const f16* base = Af + (size_t)(cg * 32 + c * 16 + fr) * NR + kq * 512 + kg * 8;
        #pragma unroll
        for (int kk = 0; kk < 16; ++kk)
            bf[c][kk] = *(const f16x8*)(base + kk * 32);
    }
    #pragma unroll
    for (int c = 0; c < 2; ++c)
        #pragma unroll
        for (int kk = 0; kk < 16; ++kk)
            asm volatile("" : "+v"(bf[c][kk]));   // pin: no remat after fences

    // ---- input-projection B slice (wave 3 only; K = 96 padded)
    f16x8 bp[2][3];
    if (kq == 3) {
        #pragma unroll
        for (int c = 0; c < 2; ++c) {
            const f16* base = Bp + (size_t)(cg * 32 + c * 16 + fr) * NUP + kg * 8;
            #pragma unroll
            for (int k2 = 0; k2 < 3; ++k2) {
                bp[c][k2] = *(const f16x8*)(base + k2 * 32);
                asm volatile("" : "+v"(bp[c][k2]));
            }
        }
    }

    // ---- fp32 master state: wave kq owns tile (rt, ct)
    float rm[4];
    #pragma unroll
    for (int i = 0; i < 4; ++i)
        rm[i] = r0[(size_t)(rt * 16 + kg * 4 + i) * NR + cg * 32 + ct * 16 + fr];

    f16* rcur = rb0a;
    f16* rnxt = rb1a;
    int* myflag = flags + (size_t)cg * FLAG_STRIDE;
    int* pollp  = flags + (size_t)(kq * 16 + (lane & 15)) * FLAG_STRIDE;

    for (int s = 0; s < NS; ++s) {
        // -- xp loads issued BEFORE the poll (latency hides under it)
        f16x8 q0, q1, q2, q3, q4, q5;
        if (kq == 3) {
            const f16* xb0 = xp + ((size_t)s * NB + fr) * NUP + kg * 8;
            q0 = *(const f16x8*)(xb0);
            q1 = *(const f16x8*)(xb0 + 32);
            q2 = *(const f16x8*)(xb0 + 64);
            const f16* xb1 = xb0 + 16 * NUP;
            q3 = *(const f16x8*)(xb1);
            q4 = *(const f16x8*)(xb1 + 32);
            q5 = *(const f16x8*)(xb1 + 64);
        }
        // -- per-wave poll: only my quarter's 16 producers
        if (s) {
            const int tgt = s;
            while (true) {
                int v = 0x7fffffff;
                if (lane < 16)
                    v = __hip_atomic_load(pollp, __ATOMIC_RELAXED,
                                          __HIP_MEMORY_SCOPE_AGENT);
                if (__all(v >= tgt)) break;
                __builtin_amdgcn_s_sleep(1);
            }
            // compiler's waitcnt for v => vmcnt drained before the asm loads
        }

        f32x4 a00 = {0,0,0,0}, a01 = {0,0,0,0}, a10 = {0,0,0,0}, a11 = {0,0,0,0};
        // consume xp first (register operands; also forces vmcnt drain at s==0)
        if (kq == 3) {
            a00 = MFMA(q0, bp[0][0], a00); a01 = MFMA(q0, bp[1][0], a01);
            a10 = MFMA(q3, bp[0][0], a10); a11 = MFMA(q3, bp[1][0], a11);
            a00 = MFMA(q1, bp[0][1], a00); a01 = MFMA(q1, bp[1][1], a01);
            a10 = MFMA(q4, bp[0][1], a10); a11 = MFMA(q4, bp[1][1], a11);
            a00 = MFMA(q2, bp[0][2], a00); a01 = MFMA(q2, bp[1][2], a01);
            a10 = MFMA(q5, bp[0][2], a10); a11 = MFMA(q5, bp[1][2], a11);
        }

        // -- device-coherent r loads, 16-frag window, counted waits
        const f16* rp0 = rcur + (size_t)fr * NR + kq * 512 + kg * 8;   // row-tile 0
        const f16* rp1 = rp0 + 16 * NR;                                 // row-tile 1
        f16x8 x[32];   // x[2k+rt] = r[rt*16+fr][kq*512 + k*32 + kg*8 ..+8]
        #define LDX(j) asm volatile("global_load_dwordx4 %0, %1, off offset:%2 sc0 sc1" \
            : "=v"(x[j]) : "v"(((j) & 1) ? rp1 : rp0), "n"(((j) >> 1) * 64) : "memory")
        #define MFG(kk) \
            a00 = MFMA(x[2*(kk)],   bf[0][kk], a00); \
            a01 = MFMA(x[2*(kk)],   bf[1][kk], a01); \
            a10 = MFMA(x[2*(kk)+1], bf[0][kk], a10); \
            a11 = MFMA(x[2*(kk)+1], bf[1][kk], a11);
        #define WAITV(n) asm volatile("s_waitcnt vmcnt(" #n ")" ::: "memory"); \
            __builtin_amdgcn_sched_barrier(0)

        LDX(0);  LDX(1);  LDX(2);  LDX(3);  LDX(4);  LDX(5);  LDX(6);  LDX(7);
        LDX(8);  LDX(9);  LDX(10); LDX(11); LDX(12); LDX(13); LDX(14); LDX(15);
        WAITV(8);
        MFG(0); MFG(1); MFG(2); MFG(3);
        __builtin_amdgcn_sched_barrier(0);
        LDX(16); LDX(17); LDX(18); LDX(19); LDX(20); LDX(21); LDX(22); LDX(23);
        WAITV(8);
        MFG(4); MFG(5); MFG(6); MFG(7);
        __builtin_amdgcn_sched_barrier(0);
        LDX(24); LDX(25); LDX(26); LDX(27); LDX(28); LDX(29); LDX(30); LDX(31);
        WAITV(8);
        MFG(8); MFG(9); MFG(10); MFG(11);
        WAITV(0);
        MFG(12); MFG(13); MFG(14); MFG(15);
        #undef LDX
        #undef MFG
        #undef WAITV

        // -- cross-wave K reduction in LDS
        lds_part[kq][0][lane] = a00;
        lds_part[kq][1][lane] = a01;
        lds_part[kq][2][lane] = a10;
        lds_part[kq][3][lane] = a11;
        __syncthreads();   // joins all 4 waves => union of all 64 flag checks

        const int tile = kq;   // (rt*2+ct) == kq
        f32x4 sum = lds_part[0][tile][lane] + lds_part[1][tile][lane]
                  + lds_part[2][tile][lane] + lds_part[3][tile][lane];

        float rn[4];
        #pragma unroll
        for (int i = 0; i < 4; ++i) {
            float sval = sum[i] + SIGMA_B;
            float v = (1.0f - ALPHA) * rm[i] + ALPHA * tanhf(sval);
            rm[i] = v;
            rn[i] = v;
            lds_r[(rt * 16 + kg * 4 + i) * 36 + ct * 16 + fr] = (f16)v;
        }
        __syncthreads();   // lds_r complete

        if (s != NS - 1) {
            // coalesced device-coherent publish: 32 rows x 64B
            int row = tid >> 3, seg = tid & 7;
            unsigned long long v = *(const unsigned long long*)&lds_r[row * 36 + seg * 4];
            asm volatile("global_store_dwordx2 %0, %1, off sc0 sc1"
                         :: "v"(rnxt + (size_t)row * NR + cg * 32 + seg * 4), "v"(v)
                         : "memory");
            asm volatile("s_waitcnt vmcnt(0)" ::: "memory");  // acked at CP
            __syncthreads();
            if (tid == 0)
                __hip_atomic_store(myflag, s + 1, __ATOMIC_RELAXED,
                                   __HIP_MEMORY_SCOPE_AGENT);
        }

        // -- output stream (off the flag critical path)
        #pragma unroll
        for (int i = 0; i < 4; ++i)
            __builtin_nontemporal_store(rn[i],
                out + ((size_t)(rt * 16 + kg * 4 + i) * NS + s) * NR
                    + cg * 32 + ct * 16 + fr);

        f16* t = rcur; rcur = rnxt; rnxt = t;
    }

    // ---- final state r_final (1, 32, 2048)
    #pragma unroll
    for (int i = 0; i < 4; ++i)
        out[(size_t)NB * NS * NR
            + (size_t)(rt * 16 + kg * 4 + i) * NR + cg * 32 + ct * 16 + fr] = rm[i];
}

extern "C" void kernel_launch(void* const* d_in, const int* in_sizes, int n_in,
                              void* d_out, int out_size, void* d_ws, size_t ws_size,
                              hipStream_t stream)
{
    const float* input = (const float*)d_in[0];
    const float* r0    = (const float*)d_in[1];
    const float* A     = (const float*)d_in[2];
    const float* B     = (const float*)d_in[3];
    float* out = (float*)d_out;
    char* ws = (char*)d_ws;

    f16* Af  = (f16*)(ws + OFF_AF);
    f16* xp  = (f16*)(ws + OFF_XP);
    f16* Bp  = (f16*)(ws + OFF_BP);
    f16* rb0 = (f16*)(ws + OFF_RB0);
    f16* rb1 = (f16*)(ws + OFF_RB1);
    int* flg = (int*)(ws + OFF_FLG);

    hipMemsetAsync(flg, 0, FLAGS_BYTES, stream);
    prep_kernel<<<2048, 256, 0, stream>>>(input, r0, A, B, Af, xp, Bp, rb0);
    scan_kernel<<<NWG, 256, 0, stream>>>(out, r0, Af, xp, Bp, rb0, rb1, flg);
}